// Round 2
// 618.529 us; speedup vs baseline: 1.0092x; 1.0092x over previous
//
#include <hip/hip_runtime.h>
#include <hip/hip_bf16.h>
#include <stdint.h>

#define N_TOK 4096
#define CDIM 2048
#define EXP 8
#define FDIM 1024

typedef __attribute__((ext_vector_type(4))) float f32x4;
typedef __attribute__((ext_vector_type(8))) short bf16x8;

// async global->LDS, 16B per lane. LDS dest must be wave-uniform (HW adds lane*16).
__device__ __forceinline__ void gl2lds16(const short* g, short* l) {
  __builtin_amdgcn_global_load_lds(
      (const __attribute__((address_space(1))) void*)g,
      (__attribute__((address_space(3))) void*)l, 16, 0, 0);
}

// ---------------- transpose + fp32->bf16: in [E][R][Cc] -> out [E][Cc][R] ----------------
__global__ __launch_bounds__(256) void transpose_to_bf16(
    const float* __restrict__ in, __hip_bfloat16* __restrict__ out, int R, int Cc) {
  __shared__ float tile[64][65];
  int e = blockIdx.z;
  const float* ip = in + (size_t)e * R * Cc;
  __hip_bfloat16* op = out + (size_t)e * R * Cc;
  int r0 = blockIdx.y * 64, c0 = blockIdx.x * 64;
  int t = threadIdx.x;
  {
    int r = t >> 2, cb = (t & 3) * 16;
    const float* src = ip + (size_t)(r0 + r) * Cc + c0 + cb;
#pragma unroll
    for (int i = 0; i < 4; i++) {
      float4 v = *(const float4*)(src + i * 4);
      tile[cb + i * 4 + 0][r] = v.x;
      tile[cb + i * 4 + 1][r] = v.y;
      tile[cb + i * 4 + 2][r] = v.z;
      tile[cb + i * 4 + 3][r] = v.w;
    }
  }
  __syncthreads();
  {
    int c = t >> 2, sb = (t & 3) * 16;
    union { int4 v[2]; __hip_bfloat16 h[16]; } u;
#pragma unroll
    for (int j = 0; j < 16; j++) u.h[j] = __float2bfloat16(tile[c][sb + j]);
    __hip_bfloat16* dst = op + (size_t)(c0 + c) * R + r0 + sb;
    *(int4*)(dst) = u.v[0];
    *(int4*)(dst + 8) = u.v[1];
  }
}

// ---------------- fp32 router + x->bf16 ----------------
__global__ __launch_bounds__(256) void router_kernel(
    const float* __restrict__ x, const float* __restrict__ wr,
    __hip_bfloat16* __restrict__ x_bf, int* __restrict__ counts,
    int* __restrict__ pair_expert, float* __restrict__ pair_prob) {
  int tok = blockIdx.x;
  const float* xr = x + (size_t)tok * CDIM;
  int t = threadIdx.x;
  float acc[EXP];
#pragma unroll
  for (int e = 0; e < EXP; e++) acc[e] = 0.f;
#pragma unroll
  for (int j = 0; j < 8; j++) {
    int c = j * 256 + t;
    float xv = xr[c];
    x_bf[(size_t)tok * CDIM + c] = __float2bfloat16(xv);
    const float4* wr4 = (const float4*)(wr + (size_t)c * EXP);
    float4 wa = wr4[0], wb = wr4[1];
    acc[0] += xv * wa.x; acc[1] += xv * wa.y; acc[2] += xv * wa.z; acc[3] += xv * wa.w;
    acc[4] += xv * wb.x; acc[5] += xv * wb.y; acc[6] += xv * wb.z; acc[7] += xv * wb.w;
  }
#pragma unroll
  for (int e = 0; e < EXP; e++) {
#pragma unroll
    for (int off = 32; off > 0; off >>= 1) acc[e] += __shfl_down(acc[e], off, 64);
  }
  __shared__ float wsum[4][EXP];
  int wid = t >> 6, lane = t & 63;
  if (lane == 0) {
#pragma unroll
    for (int e = 0; e < EXP; e++) wsum[wid][e] = acc[e];
  }
  __syncthreads();
  if (t == 0) {
    float lg[EXP];
#pragma unroll
    for (int e = 0; e < EXP; e++) lg[e] = wsum[0][e] + wsum[1][e] + wsum[2][e] + wsum[3][e];
    int i0 = 0;
#pragma unroll
    for (int e = 1; e < EXP; e++) if (lg[e] > lg[i0]) i0 = e;
    int i1 = (i0 == 0) ? 1 : 0;
#pragma unroll
    for (int e = 0; e < EXP; e++) if (e != i0 && lg[e] > lg[i1]) i1 = e;
    float e1 = __expf(lg[i1] - lg[i0]);
    float p0 = 1.f / (1.f + e1);
    pair_expert[tok * 2 + 0] = i0;
    pair_expert[tok * 2 + 1] = i1;
    pair_prob[tok * 2 + 0] = p0;
    pair_prob[tok * 2 + 1] = e1 * p0;
    atomicAdd(&counts[i0], 1);
    atomicAdd(&counts[i1], 1);
  }
}

// ---------------- tiny exclusive scan over 8 counts ----------------
__global__ void scan_kernel(const int* __restrict__ counts, int* __restrict__ bases) {
  if (threadIdx.x == 0) {
    int s = 0;
    for (int e = 0; e < EXP; e++) { bases[e] = s; s += counts[e]; }
  }
}

// ---------------- scatter pairs into per-expert lists + inverse map ----------------
__global__ __launch_bounds__(256) void scatter_kernel(
    const int* __restrict__ pair_expert, const int* __restrict__ bases,
    int* __restrict__ cursors, int* __restrict__ lists, int* __restrict__ slot_map) {
  int tok = blockIdx.x * 256 + threadIdx.x;
  if (tok >= N_TOK) return;
#pragma unroll
  for (int k = 0; k < 2; k++) {
    int e = pair_expert[tok * 2 + k];
    int pos = atomicAdd(&cursors[e], 1);
    int slot = bases[e] + pos;
    lists[slot] = tok * 2 + k;
    slot_map[tok * 2 + k] = slot;
  }
}

// ---------------- GEMM1: h = silu(x@w1) * (x@w3); global_load_lds staging ----------------
__global__ __launch_bounds__(256) void gemm1_kernel(
    const __hip_bfloat16* __restrict__ xbf, const __hip_bfloat16* __restrict__ w1t,
    const __hip_bfloat16* __restrict__ w3t, const int* __restrict__ counts,
    const int* __restrict__ bases, const int* __restrict__ lists,
    __hip_bfloat16* __restrict__ h) {
  int e = blockIdx.z;
  int n_e = counts[e];
  int m0 = blockIdx.y * 128;
  if (m0 >= n_e) return;
  int base = bases[e];
  int f0 = blockIdx.x * 64;

  // linear layouts (required by global_load_lds): stride 32 shorts = 64B rows
  __shared__ short As[128 * 32];
  __shared__ short B1s[64 * 32];
  __shared__ short B3s[64 * 32];

  int t = threadIdx.x;
  int lane = t & 63, wid = t >> 6;

  // staging map: thread t covers row (t>>2), shorts [(t&3)*8, +8) == LDS bytes [t*16, +16)
  int rowA = t >> 2, sub = (t & 3) * 8;
  int r1 = m0 + rowA, r2 = m0 + 64 + rowA;
  int tok1 = lists[base + ((r1 < n_e) ? r1 : 0)] >> 1;
  int tok2 = lists[base + ((r2 < n_e) ? r2 : 0)] >> 1;

  const short* xs = (const short*)xbf;
  const short* ag1 = xs + (size_t)tok1 * CDIM + sub;
  const short* ag2 = xs + (size_t)tok2 * CDIM + sub;
  const short* b1g = (const short*)w1t + (size_t)e * FDIM * CDIM + (size_t)(f0 + rowA) * CDIM + sub;
  const short* b3g = (const short*)w3t + (size_t)e * FDIM * CDIM + (size_t)(f0 + rowA) * CDIM + sub;

  // wave-uniform LDS bases; lane lands at +lane*16B
  short* al1 = As + wid * 512;
  short* al2 = As + 2048 + wid * 512;
  short* b1l = B1s + wid * 512;
  short* b3l = B3s + wid * 512;

  f32x4 zero = {0.f, 0.f, 0.f, 0.f};
  f32x4 accg[4][2], accu[4][2];
#pragma unroll
  for (int i = 0; i < 4; i++)
#pragma unroll
    for (int j = 0; j < 2; j++) { accg[i][j] = zero; accu[i][j] = zero; }

  int wm = (wid & 1) * 64, wf = (wid >> 1) * 32;
  int kq = (lane >> 4) * 8;
  int rsel = lane & 15;

  for (int kk = 0; kk < CDIM; kk += 32) {
    __syncthreads();  // prior tile's ds_reads done before overwrite
    gl2lds16(ag1 + kk, al1);
    gl2lds16(ag2 + kk, al2);
    gl2lds16(b1g + kk, b1l);
    gl2lds16(b3g + kk, b3l);
    __syncthreads();  // drains vmcnt -> tile resident
    bf16x8 af[4], b1f[2], b3f[2];
#pragma unroll
    for (int i = 0; i < 4; i++)
      af[i] = *(const bf16x8*)(As + (wm + i * 16 + rsel) * 32 + kq);
#pragma unroll
    for (int j = 0; j < 2; j++) {
      b1f[j] = *(const bf16x8*)(B1s + (wf + j * 16 + rsel) * 32 + kq);
      b3f[j] = *(const bf16x8*)(B3s + (wf + j * 16 + rsel) * 32 + kq);
    }
#pragma unroll
    for (int i = 0; i < 4; i++)
#pragma unroll
      for (int j = 0; j < 2; j++) {
        accg[i][j] = __builtin_amdgcn_mfma_f32_16x16x32_bf16(af[i], b1f[j], accg[i][j], 0, 0, 0);
        accu[i][j] = __builtin_amdgcn_mfma_f32_16x16x32_bf16(af[i], b3f[j], accu[i][j], 0, 0, 0);
      }
  }

  int col = lane & 15;
  int rbase = (lane >> 4) * 4;
#pragma unroll
  for (int i = 0; i < 4; i++) {
#pragma unroll
    for (int r = 0; r < 4; r++) {
      int m = m0 + wm + i * 16 + rbase + r;
      if (m < n_e) {
        size_t hrow = (size_t)(base + m) * FDIM;
#pragma unroll
        for (int j = 0; j < 2; j++) {
          int f = f0 + wf + j * 16 + col;
          float g = accg[i][j][r];
          float u = accu[i][j][r];
          float sg = g / (1.f + __expf(-g));
          h[hrow + f] = __float2bfloat16(sg * u);
        }
      }
    }
  }
}

// ---------------- GEMM2: o_pair[slot] = h[slot] @ w2 ; plain stores, no atomics ----------------
__global__ __launch_bounds__(256) void gemm2_kernel(
    const __hip_bfloat16* __restrict__ h, const __hip_bfloat16* __restrict__ w2t,
    const int* __restrict__ counts, const int* __restrict__ bases,
    float* __restrict__ o_pair) {
  int e = blockIdx.z;
  int n_e = counts[e];
  int m0 = blockIdx.y * 128;
  if (m0 >= n_e) return;
  int base = bases[e];
  int c0 = blockIdx.x * 128;

  __shared__ short As[128 * 32];
  __shared__ short Bs[128 * 32];

  int t = threadIdx.x;
  int lane = t & 63, wid = t >> 6;

  int rowA = t >> 2, sub = (t & 3) * 8;
  int hr1 = base + m0 + rowA;
  int hr2 = base + m0 + 64 + rowA;
  if (hr1 > 2 * N_TOK - 1) hr1 = 2 * N_TOK - 1;
  if (hr2 > 2 * N_TOK - 1) hr2 = 2 * N_TOK - 1;
  const short* hp = (const short*)h;
  const short* bp = (const short*)w2t + (size_t)e * CDIM * FDIM;
  const short* ag1 = hp + (size_t)hr1 * FDIM + sub;
  const short* ag2 = hp + (size_t)hr2 * FDIM + sub;
  const short* bg1 = bp + (size_t)(c0 + rowA) * FDIM + sub;
  const short* bg2 = bp + (size_t)(c0 + 64 + rowA) * FDIM + sub;

  short* al1 = As + wid * 512;
  short* al2 = As + 2048 + wid * 512;
  short* bl1 = Bs + wid * 512;
  short* bl2 = Bs + 2048 + wid * 512;

  f32x4 zero = {0.f, 0.f, 0.f, 0.f};
  f32x4 acc[4][4];
#pragma unroll
  for (int i = 0; i < 4; i++)
#pragma unroll
    for (int j = 0; j < 4; j++) acc[i][j] = zero;

  int wm = (wid & 1) * 64, wn = (wid >> 1) * 64;
  int kq = (lane >> 4) * 8;
  int rsel = lane & 15;

  for (int kk = 0; kk < FDIM; kk += 32) {
    __syncthreads();
    gl2lds16(ag1 + kk, al1);
    gl2lds16(ag2 + kk, al2);
    gl2lds16(bg1 + kk, bl1);
    gl2lds16(bg2 + kk, bl2);
    __syncthreads();
    bf16x8 af[4], bfr[4];
#pragma unroll
    for (int i = 0; i < 4; i++)
      af[i] = *(const bf16x8*)(As + (wm + i * 16 + rsel) * 32 + kq);
#pragma unroll
    for (int j = 0; j < 4; j++)
      bfr[j] = *(const bf16x8*)(Bs + (wn + j * 16 + rsel) * 32 + kq);
#pragma unroll
    for (int i = 0; i < 4; i++)
#pragma unroll
      for (int j = 0; j < 4; j++)
        acc[i][j] = __builtin_amdgcn_mfma_f32_16x16x32_bf16(af[i], bfr[j], acc[i][j], 0, 0, 0);
  }

  int col = lane & 15;
  int rbase = (lane >> 4) * 4;
#pragma unroll
  for (int i = 0; i < 4; i++) {
#pragma unroll
    for (int r = 0; r < 4; r++) {
      int m = m0 + wm + i * 16 + rbase + r;
      if (m < n_e) {
        size_t orow = (size_t)(base + m) * CDIM;
#pragma unroll
        for (int j = 0; j < 4; j++) {
          int c = c0 + wn + j * 16 + col;
          o_pair[orow + c] = acc[i][j][r];
        }
      }
    }
  }
}

// ---------------- combine: out[tok] = p0*o_pair[s0] + p1*o_pair[s1] ----------------
__global__ __launch_bounds__(256) void combine_kernel(
    const float* __restrict__ o_pair, const int* __restrict__ slot_map,
    const float* __restrict__ pair_prob, float* __restrict__ out) {
  int tok = blockIdx.x;
  int s0 = slot_map[tok * 2 + 0], s1 = slot_map[tok * 2 + 1];
  float p0 = pair_prob[tok * 2 + 0], p1 = pair_prob[tok * 2 + 1];
  const float4* r0 = (const float4*)(o_pair + (size_t)s0 * CDIM);
  const float4* r1 = (const float4*)(o_pair + (size_t)s1 * CDIM);
  float4* op = (float4*)(out + (size_t)tok * CDIM);
  int t = threadIdx.x;
#pragma unroll
  for (int j = 0; j < 2; j++) {
    int i = j * 256 + t;
    float4 a = r0[i], b = r1[i];
    float4 c;
    c.x = p0 * a.x + p1 * b.x;
    c.y = p0 * a.y + p1 * b.y;
    c.z = p0 * a.z + p1 * b.z;
    c.w = p0 * a.w + p1 * b.w;
    op[i] = c;
  }
}

extern "C" void kernel_launch(void* const* d_in, const int* in_sizes, int n_in,
                              void* d_out, int out_size, void* d_ws, size_t ws_size,
                              hipStream_t stream) {
  const float* x  = (const float*)d_in[0];
  const float* wr = (const float*)d_in[1];
  const float* w1 = (const float*)d_in[2];
  const float* w3 = (const float*)d_in[3];
  const float* w2 = (const float*)d_in[4];
  float* out = (float*)d_out;

  char* ws = (char*)d_ws;
  __hip_bfloat16* x_bf = (__hip_bfloat16*)(ws);                 // 16 MiB
  __hip_bfloat16* h    = (__hip_bfloat16*)(ws + 16777216);      // 16 MiB
  __hip_bfloat16* w1t  = (__hip_bfloat16*)(ws + 33554432);      // 32 MiB
  __hip_bfloat16* w3t  = (__hip_bfloat16*)(ws + 67108864);      // 32 MiB
  __hip_bfloat16* w2t  = (__hip_bfloat16*)(ws + 100663296);     // 32 MiB
  // o_pair (8192 x 2048 fp32 = 64 MiB) aliases [w1t, w3t] — both dead after gemm1
  float* o_pair = (float*)(ws + 33554432);
  int* counts  = (int*)(ws + 134217728);
  int* bases   = counts + 8;
  int* cursors = counts + 16;
  int* pair_expert = (int*)(ws + 134217728 + 128);
  float* pair_prob = (float*)(ws + 134217728 + 128 + 32768);
  int* lists       = (int*)(ws + 134217728 + 128 + 65536);
  int* slot_map    = (int*)(ws + 134217728 + 128 + 98304);

  hipMemsetAsync(counts, 0, 128, stream);

  // w1,w3: [E][C][F] -> [E][F][C] bf16 ; w2: [E][F][C] -> [E][C][F] bf16
  transpose_to_bf16<<<dim3(FDIM / 64, CDIM / 64, EXP), 256, 0, stream>>>(w1, w1t, CDIM, FDIM);
  transpose_to_bf16<<<dim3(FDIM / 64, CDIM / 64, EXP), 256, 0, stream>>>(w3, w3t, CDIM, FDIM);
  transpose_to_bf16<<<dim3(CDIM / 64, FDIM / 64, EXP), 256, 0, stream>>>(w2, w2t, FDIM, CDIM);

  router_kernel<<<N_TOK, 256, 0, stream>>>(x, wr, x_bf, counts, pair_expert, pair_prob);
  scan_kernel<<<1, 64, 0, stream>>>(counts, bases);
  scatter_kernel<<<N_TOK / 256, 256, 0, stream>>>(pair_expert, bases, cursors, lists, slot_map);

  gemm1_kernel<<<dim3(FDIM / 64, N_TOK / 128, EXP), 256, 0, stream>>>(
      x_bf, w1t, w3t, counts, bases, lists, h);
  gemm2_kernel<<<dim3(CDIM / 128, N_TOK / 128, EXP), 256, 0, stream>>>(
      h, w2t, counts, bases, o_pair);
  combine_kernel<<<N_TOK, 256, 0, stream>>>(o_pair, slot_map, pair_prob, out);
}

// Round 3
// 614.207 us; speedup vs baseline: 1.0163x; 1.0070x over previous
//
#include <hip/hip_runtime.h>
#include <hip/hip_bf16.h>
#include <stdint.h>

#define N_TOK 4096
#define CDIM 2048
#define EXP 8
#define FDIM 1024

typedef __attribute__((ext_vector_type(4))) float f32x4;
typedef __attribute__((ext_vector_type(8))) short bf16x8;

// async global->LDS, 16B per lane. LDS dest must be wave-uniform (HW adds lane*16).
__device__ __forceinline__ void gl2lds16(const short* g, short* l) {
  __builtin_amdgcn_global_load_lds(
      (const __attribute__((address_space(1))) void*)g,
      (__attribute__((address_space(3))) void*)l, 16, 0, 0);
}

#define SBAR() __builtin_amdgcn_s_barrier()
#define SCHED0() __builtin_amdgcn_sched_barrier(0)

// ---------------- transpose + fp32->bf16: in [E][R][Cc] -> out [E][Cc][R] ----------------
__global__ __launch_bounds__(256) void transpose_to_bf16(
    const float* __restrict__ in, __hip_bfloat16* __restrict__ out, int R, int Cc) {
  __shared__ float tile[64][65];
  int e = blockIdx.z;
  const float* ip = in + (size_t)e * R * Cc;
  __hip_bfloat16* op = out + (size_t)e * R * Cc;
  int r0 = blockIdx.y * 64, c0 = blockIdx.x * 64;
  int t = threadIdx.x;
  {
    int r = t >> 2, cb = (t & 3) * 16;
    const float* src = ip + (size_t)(r0 + r) * Cc + c0 + cb;
#pragma unroll
    for (int i = 0; i < 4; i++) {
      float4 v = *(const float4*)(src + i * 4);
      tile[cb + i * 4 + 0][r] = v.x;
      tile[cb + i * 4 + 1][r] = v.y;
      tile[cb + i * 4 + 2][r] = v.z;
      tile[cb + i * 4 + 3][r] = v.w;
    }
  }
  __syncthreads();
  {
    int c = t >> 2, sb = (t & 3) * 16;
    union { int4 v[2]; __hip_bfloat16 h[16]; } u;
#pragma unroll
    for (int j = 0; j < 16; j++) u.h[j] = __float2bfloat16(tile[c][sb + j]);
    __hip_bfloat16* dst = op + (size_t)(c0 + c) * R + r0 + sb;
    *(int4*)(dst) = u.v[0];
    *(int4*)(dst + 8) = u.v[1];
  }
}

// ---------------- fp32 router + x->bf16 ----------------
__global__ __launch_bounds__(256) void router_kernel(
    const float* __restrict__ x, const float* __restrict__ wr,
    __hip_bfloat16* __restrict__ x_bf, int* __restrict__ counts,
    int* __restrict__ pair_expert, float* __restrict__ pair_prob) {
  int tok = blockIdx.x;
  const float* xr = x + (size_t)tok * CDIM;
  int t = threadIdx.x;
  float acc[EXP];
#pragma unroll
  for (int e = 0; e < EXP; e++) acc[e] = 0.f;
#pragma unroll
  for (int j = 0; j < 8; j++) {
    int c = j * 256 + t;
    float xv = xr[c];
    x_bf[(size_t)tok * CDIM + c] = __float2bfloat16(xv);
    const float4* wr4 = (const float4*)(wr + (size_t)c * EXP);
    float4 wa = wr4[0], wb = wr4[1];
    acc[0] += xv * wa.x; acc[1] += xv * wa.y; acc[2] += xv * wa.z; acc[3] += xv * wa.w;
    acc[4] += xv * wb.x; acc[5] += xv * wb.y; acc[6] += xv * wb.z; acc[7] += xv * wb.w;
  }
#pragma unroll
  for (int e = 0; e < EXP; e++) {
#pragma unroll
    for (int off = 32; off > 0; off >>= 1) acc[e] += __shfl_down(acc[e], off, 64);
  }
  __shared__ float wsum[4][EXP];
  int wid = t >> 6, lane = t & 63;
  if (lane == 0) {
#pragma unroll
    for (int e = 0; e < EXP; e++) wsum[wid][e] = acc[e];
  }
  __syncthreads();
  if (t == 0) {
    float lg[EXP];
#pragma unroll
    for (int e = 0; e < EXP; e++) lg[e] = wsum[0][e] + wsum[1][e] + wsum[2][e] + wsum[3][e];
    int i0 = 0;
#pragma unroll
    for (int e = 1; e < EXP; e++) if (lg[e] > lg[i0]) i0 = e;
    int i1 = (i0 == 0) ? 1 : 0;
#pragma unroll
    for (int e = 0; e < EXP; e++) if (e != i0 && lg[e] > lg[i1]) i1 = e;
    float e1 = __expf(lg[i1] - lg[i0]);
    float p0 = 1.f / (1.f + e1);
    pair_expert[tok * 2 + 0] = i0;
    pair_expert[tok * 2 + 1] = i1;
    pair_prob[tok * 2 + 0] = p0;
    pair_prob[tok * 2 + 1] = e1 * p0;
    atomicAdd(&counts[i0], 1);
    atomicAdd(&counts[i1], 1);
  }
}

// ---------------- tiny exclusive scan over 8 counts ----------------
__global__ void scan_kernel(const int* __restrict__ counts, int* __restrict__ bases) {
  if (threadIdx.x == 0) {
    int s = 0;
    for (int e = 0; e < EXP; e++) { bases[e] = s; s += counts[e]; }
  }
}

// ---------------- scatter pairs into per-expert lists + inverse map ----------------
__global__ __launch_bounds__(256) void scatter_kernel(
    const int* __restrict__ pair_expert, const int* __restrict__ bases,
    int* __restrict__ cursors, int* __restrict__ lists, int* __restrict__ slot_map) {
  int tok = blockIdx.x * 256 + threadIdx.x;
  if (tok >= N_TOK) return;
#pragma unroll
  for (int k = 0; k < 2; k++) {
    int e = pair_expert[tok * 2 + k];
    int pos = atomicAdd(&cursors[e], 1);
    int slot = bases[e] + pos;
    lists[slot] = tok * 2 + k;
    slot_map[tok * 2 + k] = slot;
  }
}

// ---------------- GEMM1: h = silu(x@w1) * (x@w3) ----------------
// dbuf LDS + global_load_lds + counted vmcnt(4); XOR chunk-swizzle (both sides).
__global__ __launch_bounds__(256) void gemm1_kernel(
    const __hip_bfloat16* __restrict__ xbf, const __hip_bfloat16* __restrict__ w1t,
    const __hip_bfloat16* __restrict__ w3t, const int* __restrict__ counts,
    const int* __restrict__ bases, const int* __restrict__ lists,
    __hip_bfloat16* __restrict__ h) {
  int e = blockIdx.z;
  int n_e = counts[e];
  int m0 = blockIdx.y * 128;
  if (m0 >= n_e) return;
  int base = bases[e];
  int f0 = blockIdx.x * 64;

  // [2 buffers] linear rows of 32 shorts (64B); A 128 rows, B1/B3 64 rows each
  __shared__ short As[2 * 4096];
  __shared__ short B1s[2 * 2048];
  __shared__ short B3s[2 * 2048];

  int t = threadIdx.x;
  int lane = t & 63, wid = t >> 6;

  // staging: thread t covers row (t>>2), LDS chunk (t&3); global chunk XOR-swizzled
  int rowA = t >> 2;
  int cswz = (t & 3) ^ ((rowA >> 1) & 3);
  int sub = cswz * 8;  // shorts
  int r1 = m0 + rowA, r2 = m0 + 64 + rowA;
  int tok1 = lists[base + ((r1 < n_e) ? r1 : 0)] >> 1;
  int tok2 = lists[base + ((r2 < n_e) ? r2 : 0)] >> 1;

  const short* xs = (const short*)xbf;
  const short* ag1 = xs + (size_t)tok1 * CDIM + sub;
  const short* ag2 = xs + (size_t)tok2 * CDIM + sub;
  const short* b1g = (const short*)w1t + (size_t)e * FDIM * CDIM + (size_t)(f0 + rowA) * CDIM + sub;
  const short* b3g = (const short*)w3t + (size_t)e * FDIM * CDIM + (size_t)(f0 + rowA) * CDIM + sub;

  int aoff = wid * 512;  // wave-uniform; lane lands at +lane*16B

  // prologue: tile 0 -> buf 0
  gl2lds16(ag1, As + aoff);
  gl2lds16(ag2, As + 2048 + aoff);
  gl2lds16(b1g, B1s + aoff);
  gl2lds16(b3g, B3s + aoff);

  f32x4 zero = {0.f, 0.f, 0.f, 0.f};
  f32x4 accg[4][2], accu[4][2];
#pragma unroll
  for (int i = 0; i < 4; i++)
#pragma unroll
    for (int j = 0; j < 2; j++) { accg[i][j] = zero; accu[i][j] = zero; }

  int wm = (wid & 1) * 64, wf = (wid >> 1) * 32;
  int rsel = lane & 15;
  // read-side swizzle: LDS chunk = wanted_chunk(lane>>4) ^ ((row>>1)&3); row%8 == rsel%8
  int kq_swz = (((lane >> 4) ^ ((lane >> 1) & 3))) * 8;

#pragma unroll 2
  for (int tt = 0; tt < CDIM / 32; ++tt) {
    int cb = tt & 1;
    if (tt < CDIM / 32 - 1) {
      int nb = cb ^ 1;
      int kk = (tt + 1) * 32;
      gl2lds16(ag1 + kk, As + nb * 4096 + aoff);
      gl2lds16(ag2 + kk, As + nb * 4096 + 2048 + aoff);
      gl2lds16(b1g + kk, B1s + nb * 2048 + aoff);
      gl2lds16(b3g + kk, B3s + nb * 2048 + aoff);
      asm volatile("s_waitcnt vmcnt(4)" ::: "memory");  // tile tt resident; tile tt+1 in flight
    } else {
      asm volatile("s_waitcnt vmcnt(0)" ::: "memory");
    }
    SCHED0();
    SBAR();
    SCHED0();
    bf16x8 af[4], b1f[2], b3f[2];
#pragma unroll
    for (int i = 0; i < 4; i++)
      af[i] = *(const bf16x8*)(As + cb * 4096 + (wm + i * 16 + rsel) * 32 + kq_swz);
#pragma unroll
    for (int j = 0; j < 2; j++) {
      b1f[j] = *(const bf16x8*)(B1s + cb * 2048 + (wf + j * 16 + rsel) * 32 + kq_swz);
      b3f[j] = *(const bf16x8*)(B3s + cb * 2048 + (wf + j * 16 + rsel) * 32 + kq_swz);
    }
#pragma unroll
    for (int i = 0; i < 4; i++)
#pragma unroll
      for (int j = 0; j < 2; j++) {
        accg[i][j] = __builtin_amdgcn_mfma_f32_16x16x32_bf16(af[i], b1f[j], accg[i][j], 0, 0, 0);
        accu[i][j] = __builtin_amdgcn_mfma_f32_16x16x32_bf16(af[i], b3f[j], accu[i][j], 0, 0, 0);
      }
    SCHED0();
    SBAR();  // all waves done reading buf cb before next iter overwrites it
  }

  int col = lane & 15;
  int rbase = (lane >> 4) * 4;
#pragma unroll
  for (int i = 0; i < 4; i++) {
#pragma unroll
    for (int r = 0; r < 4; r++) {
      int m = m0 + wm + i * 16 + rbase + r;
      if (m < n_e) {
        size_t hrow = (size_t)(base + m) * FDIM;
#pragma unroll
        for (int j = 0; j < 2; j++) {
          int f = f0 + wf + j * 16 + col;
          float g = accg[i][j][r];
          float u = accu[i][j][r];
          float sg = g / (1.f + __expf(-g));
          h[hrow + f] = __float2bfloat16(sg * u);
        }
      }
    }
  }
}

// ---------------- GEMM2: o_pair[slot] = h[slot] @ w2 ; same pipeline, no atomics ----------------
__global__ __launch_bounds__(256) void gemm2_kernel(
    const __hip_bfloat16* __restrict__ h, const __hip_bfloat16* __restrict__ w2t,
    const int* __restrict__ counts, const int* __restrict__ bases,
    float* __restrict__ o_pair) {
  int e = blockIdx.z;
  int n_e = counts[e];
  int m0 = blockIdx.y * 128;
  if (m0 >= n_e) return;
  int base = bases[e];
  int c0 = blockIdx.x * 128;

  __shared__ short As[2 * 4096];
  __shared__ short Bs[2 * 4096];

  int t = threadIdx.x;
  int lane = t & 63, wid = t >> 6;

  int rowA = t >> 2;
  int cswz = (t & 3) ^ ((rowA >> 1) & 3);
  int sub = cswz * 8;
  int hr1 = base + m0 + rowA;
  int hr2 = base + m0 + 64 + rowA;
  if (hr1 > 2 * N_TOK - 1) hr1 = 2 * N_TOK - 1;
  if (hr2 > 2 * N_TOK - 1) hr2 = 2 * N_TOK - 1;
  const short* hp = (const short*)h;
  const short* bp = (const short*)w2t + (size_t)e * CDIM * FDIM;
  const short* ag1 = hp + (size_t)hr1 * FDIM + sub;
  const short* ag2 = hp + (size_t)hr2 * FDIM + sub;
  const short* bg1 = bp + (size_t)(c0 + rowA) * FDIM + sub;
  const short* bg2 = bp + (size_t)(c0 + 64 + rowA) * FDIM + sub;

  int aoff = wid * 512;

  gl2lds16(ag1, As + aoff);
  gl2lds16(ag2, As + 2048 + aoff);
  gl2lds16(bg1, Bs + aoff);
  gl2lds16(bg2, Bs + 2048 + aoff);

  f32x4 zero = {0.f, 0.f, 0.f, 0.f};
  f32x4 acc[4][4];
#pragma unroll
  for (int i = 0; i < 4; i++)
#pragma unroll
    for (int j = 0; j < 4; j++) acc[i][j] = zero;

  int wm = (wid & 1) * 64, wn = (wid >> 1) * 64;
  int rsel = lane & 15;
  int kq_swz = (((lane >> 4) ^ ((lane >> 1) & 3))) * 8;

#pragma unroll 2
  for (int tt = 0; tt < FDIM / 32; ++tt) {
    int cb = tt & 1;
    if (tt < FDIM / 32 - 1) {
      int nb = cb ^ 1;
      int kk = (tt + 1) * 32;
      gl2lds16(ag1 + kk, As + nb * 4096 + aoff);
      gl2lds16(ag2 + kk, As + nb * 4096 + 2048 + aoff);
      gl2lds16(bg1 + kk, Bs + nb * 4096 + aoff);
      gl2lds16(bg2 + kk, Bs + nb * 4096 + 2048 + aoff);
      asm volatile("s_waitcnt vmcnt(4)" ::: "memory");
    } else {
      asm volatile("s_waitcnt vmcnt(0)" ::: "memory");
    }
    SCHED0();
    SBAR();
    SCHED0();
    bf16x8 af[4], bfr[4];
#pragma unroll
    for (int i = 0; i < 4; i++)
      af[i] = *(const bf16x8*)(As + cb * 4096 + (wm + i * 16 + rsel) * 32 + kq_swz);
#pragma unroll
    for (int j = 0; j < 4; j++)
      bfr[j] = *(const bf16x8*)(Bs + cb * 4096 + (wn + j * 16 + rsel) * 32 + kq_swz);
#pragma unroll
    for (int i = 0; i < 4; i++)
#pragma unroll
      for (int j = 0; j < 4; j++)
        acc[i][j] = __builtin_amdgcn_mfma_f32_16x16x32_bf16(af[i], bfr[j], acc[i][j], 0, 0, 0);
    SCHED0();
    SBAR();
  }

  int col = lane & 15;
  int rbase = (lane >> 4) * 4;
#pragma unroll
  for (int i = 0; i < 4; i++) {
#pragma unroll
    for (int r = 0; r < 4; r++) {
      int m = m0 + wm + i * 16 + rbase + r;
      if (m < n_e) {
        size_t orow = (size_t)(base + m) * CDIM;
#pragma unroll
        for (int j = 0; j < 4; j++) {
          int c = c0 + wn + j * 16 + col;
          o_pair[orow + c] = acc[i][j][r];
        }
      }
    }
  }
}

// ---------------- combine: out[tok] = p0*o_pair[s0] + p1*o_pair[s1] ----------------
__global__ __launch_bounds__(256) void combine_kernel(
    const float* __restrict__ o_pair, const int* __restrict__ slot_map,
    const float* __restrict__ pair_prob, float* __restrict__ out) {
  int tok = blockIdx.x;
  int s0 = slot_map[tok * 2 + 0], s1 = slot_map[tok * 2 + 1];
  float p0 = pair_prob[tok * 2 + 0], p1 = pair_prob[tok * 2 + 1];
  const float4* r0 = (const float4*)(o_pair + (size_t)s0 * CDIM);
  const float4* r1 = (const float4*)(o_pair + (size_t)s1 * CDIM);
  float4* op = (float4*)(out + (size_t)tok * CDIM);
  int t = threadIdx.x;
#pragma unroll
  for (int j = 0; j < 2; j++) {
    int i = j * 256 + t;
    float4 a = r0[i], b = r1[i];
    float4 c;
    c.x = p0 * a.x + p1 * b.x;
    c.y = p0 * a.y + p1 * b.y;
    c.z = p0 * a.z + p1 * b.z;
    c.w = p0 * a.w + p1 * b.w;
    op[i] = c;
  }
}

extern "C" void kernel_launch(void* const* d_in, const int* in_sizes, int n_in,
                              void* d_out, int out_size, void* d_ws, size_t ws_size,
                              hipStream_t stream) {
  const float* x  = (const float*)d_in[0];
  const float* wr = (const float*)d_in[1];
  const float* w1 = (const float*)d_in[2];
  const float* w3 = (const float*)d_in[3];
  const float* w2 = (const float*)d_in[4];
  float* out = (float*)d_out;

  char* ws = (char*)d_ws;
  __hip_bfloat16* x_bf = (__hip_bfloat16*)(ws);                 // 16 MiB
  __hip_bfloat16* h    = (__hip_bfloat16*)(ws + 16777216);      // 16 MiB
  __hip_bfloat16* w1t  = (__hip_bfloat16*)(ws + 33554432);      // 32 MiB
  __hip_bfloat16* w3t  = (__hip_bfloat16*)(ws + 67108864);      // 32 MiB
  __hip_bfloat16* w2t  = (__hip_bfloat16*)(ws + 100663296);     // 32 MiB
  // o_pair (8192 x 2048 fp32 = 64 MiB) aliases [w1t, w3t] — both dead after gemm1
  float* o_pair = (float*)(ws + 33554432);
  int* counts  = (int*)(ws + 134217728);
  int* bases   = counts + 8;
  int* cursors = counts + 16;
  int* pair_expert = (int*)(ws + 134217728 + 128);
  float* pair_prob = (float*)(ws + 134217728 + 128 + 32768);
  int* lists       = (int*)(ws + 134217728 + 128 + 65536);
  int* slot_map    = (int*)(ws + 134217728 + 128 + 98304);

  hipMemsetAsync(counts, 0, 128, stream);

  // w1,w3: [E][C][F] -> [E][F][C] bf16 ; w2: [E][F][C] -> [E][C][F] bf16
  transpose_to_bf16<<<dim3(FDIM / 64, CDIM / 64, EXP), 256, 0, stream>>>(w1, w1t, CDIM, FDIM);
  transpose_to_bf16<<<dim3(FDIM / 64, CDIM / 64, EXP), 256, 0, stream>>>(w3, w3t, CDIM, FDIM);
  transpose_to_bf16<<<dim3(CDIM / 64, FDIM / 64, EXP), 256, 0, stream>>>(w2, w2t, FDIM, CDIM);

  router_kernel<<<N_TOK, 256, 0, stream>>>(x, wr, x_bf, counts, pair_expert, pair_prob);
  scan_kernel<<<1, 64, 0, stream>>>(counts, bases);
  scatter_kernel<<<N_TOK / 256, 256, 0, stream>>>(pair_expert, bases, cursors, lists, slot_map);

  gemm1_kernel<<<dim3(FDIM / 64, N_TOK / 128, EXP), 256, 0, stream>>>(
      x_bf, w1t, w3t, counts, bases, lists, h);
  gemm2_kernel<<<dim3(CDIM / 128, N_TOK / 128, EXP), 256, 0, stream>>>(
      h, w2t, counts, bases, o_pair);
  combine_kernel<<<N_TOK, 256, 0, stream>>>(o_pair, slot_map, pair_prob, out);
}

// Round 5
// 613.515 us; speedup vs baseline: 1.0175x; 1.0011x over previous
//
#include <hip/hip_runtime.h>
#include <hip/hip_bf16.h>
#include <stdint.h>

#define N_TOK 4096
#define CDIM 2048
#define EXP 8
#define FDIM 1024
#define MAX_TILES 72  // sum_e ceil(n_e/128) <= 2*N_TOK/128 + EXP

typedef __attribute__((ext_vector_type(4))) float f32x4;
typedef __attribute__((ext_vector_type(8))) short bf16x8;

// async global->LDS, 16B per lane. LDS dest must be wave-uniform (HW adds lane*16).
__device__ __forceinline__ void gl2lds16(const short* g, short* l) {
  __builtin_amdgcn_global_load_lds(
      (const __attribute__((address_space(1))) void*)g,
      (__attribute__((address_space(3))) void*)l, 16, 0, 0);
}

// ---------------- transpose + fp32->bf16: in [E][R][Cc] -> out [E][Cc][R] ----------------
__global__ __launch_bounds__(256) void transpose_to_bf16(
    const float* __restrict__ in, __hip_bfloat16* __restrict__ out, int R, int Cc) {
  __shared__ float tile[64][65];
  int e = blockIdx.z;
  const float* ip = in + (size_t)e * R * Cc;
  __hip_bfloat16* op = out + (size_t)e * R * Cc;
  int r0 = blockIdx.y * 64, c0 = blockIdx.x * 64;
  int t = threadIdx.x;
  {
    int r = t >> 2, cb = (t & 3) * 16;
    const float* src = ip + (size_t)(r0 + r) * Cc + c0 + cb;
#pragma unroll
    for (int i = 0; i < 4; i++) {
      float4 v = *(const float4*)(src + i * 4);
      tile[cb + i * 4 + 0][r] = v.x;
      tile[cb + i * 4 + 1][r] = v.y;
      tile[cb + i * 4 + 2][r] = v.z;
      tile[cb + i * 4 + 3][r] = v.w;
    }
  }
  __syncthreads();
  {
    int c = t >> 2, sb = (t & 3) * 16;
    union { int4 v[2]; __hip_bfloat16 h[16]; } u;
#pragma unroll
    for (int j = 0; j < 16; j++) u.h[j] = __float2bfloat16(tile[c][sb + j]);
    __hip_bfloat16* dst = op + (size_t)(c0 + c) * R + r0 + sb;
    *(int4*)(dst) = u.v[0];
    *(int4*)(dst + 8) = u.v[1];
  }
}

// ---------------- fp32 router + x->bf16 ----------------
__global__ __launch_bounds__(256) void router_kernel(
    const float* __restrict__ x, const float* __restrict__ wr,
    __hip_bfloat16* __restrict__ x_bf, int* __restrict__ counts,
    int* __restrict__ pair_expert, float* __restrict__ pair_prob) {
  int tok = blockIdx.x;
  const float* xr = x + (size_t)tok * CDIM;
  int t = threadIdx.x;
  float acc[EXP];
#pragma unroll
  for (int e = 0; e < EXP; e++) acc[e] = 0.f;
#pragma unroll
  for (int j = 0; j < 8; j++) {
    int c = j * 256 + t;
    float xv = xr[c];
    x_bf[(size_t)tok * CDIM + c] = __float2bfloat16(xv);
    const float4* wr4 = (const float4*)(wr + (size_t)c * EXP);
    float4 wa = wr4[0], wb = wr4[1];
    acc[0] += xv * wa.x; acc[1] += xv * wa.y; acc[2] += xv * wa.z; acc[3] += xv * wa.w;
    acc[4] += xv * wb.x; acc[5] += xv * wb.y; acc[6] += xv * wb.z; acc[7] += xv * wb.w;
  }
#pragma unroll
  for (int e = 0; e < EXP; e++) {
#pragma unroll
    for (int off = 32; off > 0; off >>= 1) acc[e] += __shfl_down(acc[e], off, 64);
  }
  __shared__ float wsum[4][EXP];
  int wid = t >> 6, lane = t & 63;
  if (lane == 0) {
#pragma unroll
    for (int e = 0; e < EXP; e++) wsum[wid][e] = acc[e];
  }
  __syncthreads();
  if (t == 0) {
    float lg[EXP];
#pragma unroll
    for (int e = 0; e < EXP; e++) lg[e] = wsum[0][e] + wsum[1][e] + wsum[2][e] + wsum[3][e];
    int i0 = 0;
#pragma unroll
    for (int e = 1; e < EXP; e++) if (lg[e] > lg[i0]) i0 = e;
    int i1 = (i0 == 0) ? 1 : 0;
#pragma unroll
    for (int e = 0; e < EXP; e++) if (e != i0 && lg[e] > lg[i1]) i1 = e;
    float e1 = __expf(lg[i1] - lg[i0]);
    float p0 = 1.f / (1.f + e1);
    pair_expert[tok * 2 + 0] = i0;
    pair_expert[tok * 2 + 1] = i1;
    pair_prob[tok * 2 + 0] = p0;
    pair_prob[tok * 2 + 1] = e1 * p0;
    atomicAdd(&counts[i0], 1);
    atomicAdd(&counts[i1], 1);
  }
}

// ---------------- scan + compact tile list ----------------
__global__ void scan_kernel(const int* __restrict__ counts, int* __restrict__ bases,
                            int* __restrict__ tiles, int* __restrict__ ntiles) {
  if (threadIdx.x == 0) {
    int s = 0;
    for (int e = 0; e < EXP; e++) { bases[e] = s; s += counts[e]; }
    int nt = 0;
    for (int e = 0; e < EXP; e++)
      for (int m0 = 0; m0 < counts[e]; m0 += 128)
        tiles[nt++] = (e << 20) | m0;
    ntiles[0] = nt;
  }
}

// ---------------- scatter pairs into per-expert lists + inverse map ----------------
__global__ __launch_bounds__(256) void scatter_kernel(
    const int* __restrict__ pair_expert, const int* __restrict__ bases,
    int* __restrict__ cursors, int* __restrict__ lists, int* __restrict__ slot_map) {
  int tok = blockIdx.x * 256 + threadIdx.x;
  if (tok >= N_TOK) return;
#pragma unroll
  for (int k = 0; k < 2; k++) {
    int e = pair_expert[tok * 2 + k];
    int pos = atomicAdd(&cursors[e], 1);
    int slot = bases[e] + pos;
    lists[slot] = tok * 2 + k;
    slot_map[tok * 2 + k] = slot;
  }
}

// ---------------- GEMM1: h = silu(x@w1) * (x@w3) ----------------
// m97 structure: single-buffer LDS + global_load_lds + 2 barriers; XOR chunk swizzle.
// Compact tile list -> nearly all blocks active, dispatch-contiguous.
__global__ __launch_bounds__(256) void gemm1_kernel(
    const __hip_bfloat16* __restrict__ xbf, const __hip_bfloat16* __restrict__ w1t,
    const __hip_bfloat16* __restrict__ w3t, const int* __restrict__ counts,
    const int* __restrict__ bases, const int* __restrict__ lists,
    const int* __restrict__ tiles, const int* __restrict__ ntiles,
    __hip_bfloat16* __restrict__ h) {
  int y = blockIdx.y;
  if (y >= ntiles[0]) return;
  int packed = tiles[y];
  int e = packed >> 20;
  int m0 = packed & 0xFFFFF;
  int n_e = counts[e];
  int base = bases[e];
  int f0 = blockIdx.x * 64;

  // linear rows of 32 shorts (64B); A 128 rows, B1/B3 64 rows each
  __shared__ short As[4096];
  __shared__ short B1s[2048];
  __shared__ short B3s[2048];

  int t = threadIdx.x;
  int lane = t & 63, wid = t >> 6;

  // staging: thread t covers row (t>>2); global chunk XOR-swizzled vs LDS chunk (t&3)
  int rowA = t >> 2;
  int cswz = (t & 3) ^ ((rowA >> 1) & 3);
  int sub = cswz * 8;  // shorts
  int r1 = m0 + rowA, r2 = m0 + 64 + rowA;
  int tok1 = lists[base + ((r1 < n_e) ? r1 : 0)] >> 1;
  int tok2 = lists[base + ((r2 < n_e) ? r2 : 0)] >> 1;

  const short* xs = (const short*)xbf;
  const short* ag1 = xs + (size_t)tok1 * CDIM + sub;
  const short* ag2 = xs + (size_t)tok2 * CDIM + sub;
  const short* b1g = (const short*)w1t + (size_t)e * FDIM * CDIM + (size_t)(f0 + rowA) * CDIM + sub;
  const short* b3g = (const short*)w3t + (size_t)e * FDIM * CDIM + (size_t)(f0 + rowA) * CDIM + sub;

  int aoff = wid * 512;  // wave-uniform; lane lands at +lane*16B

  f32x4 zero = {0.f, 0.f, 0.f, 0.f};
  f32x4 accg[4][2], accu[4][2];
#pragma unroll
  for (int i = 0; i < 4; i++)
#pragma unroll
    for (int j = 0; j < 2; j++) { accg[i][j] = zero; accu[i][j] = zero; }

  int wm = (wid & 1) * 64, wf = (wid >> 1) * 32;
  int rsel = lane & 15;
  // read-side swizzle: LDS chunk = (lane>>4) ^ ((row>>1)&3); (row>>1)&3 == (lane>>1)&3
  int kq_swz = (((lane >> 4) ^ ((lane >> 1) & 3))) * 8;

  for (int kk = 0; kk < CDIM; kk += 32) {
    __syncthreads();  // prior tile's ds_reads done before overwrite
    gl2lds16(ag1 + kk, As + aoff);
    gl2lds16(ag2 + kk, As + 2048 + aoff);
    gl2lds16(b1g + kk, B1s + aoff);
    gl2lds16(b3g + kk, B3s + aoff);
    __syncthreads();  // drains vmcnt -> tile resident
    bf16x8 af[4], b1f[2], b3f[2];
#pragma unroll
    for (int i = 0; i < 4; i++)
      af[i] = *(const bf16x8*)(As + (wm + i * 16 + rsel) * 32 + kq_swz);
#pragma unroll
    for (int j = 0; j < 2; j++) {
      b1f[j] = *(const bf16x8*)(B1s + (wf + j * 16 + rsel) * 32 + kq_swz);
      b3f[j] = *(const bf16x8*)(B3s + (wf + j * 16 + rsel) * 32 + kq_swz);
    }
#pragma unroll
    for (int i = 0; i < 4; i++)
#pragma unroll
      for (int j = 0; j < 2; j++) {
        accg[i][j] = __builtin_amdgcn_mfma_f32_16x16x32_bf16(af[i], b1f[j], accg[i][j], 0, 0, 0);
        accu[i][j] = __builtin_amdgcn_mfma_f32_16x16x32_bf16(af[i], b3f[j], accu[i][j], 0, 0, 0);
      }
  }

  int col = lane & 15;
  int rbase = (lane >> 4) * 4;
#pragma unroll
  for (int i = 0; i < 4; i++) {
#pragma unroll
    for (int r = 0; r < 4; r++) {
      int m = m0 + wm + i * 16 + rbase + r;
      if (m < n_e) {
        size_t hrow = (size_t)(base + m) * FDIM;
#pragma unroll
        for (int j = 0; j < 2; j++) {
          int f = f0 + wf + j * 16 + col;
          float g = accg[i][j][r];
          float u = accu[i][j][r];
          float sg = g / (1.f + __expf(-g));
          h[hrow + f] = __float2bfloat16(sg * u);
        }
      }
    }
  }
}

// ---------------- GEMM2: o_pair[slot] = h[slot] @ w2 ; same structure, no atomics ----------------
__global__ __launch_bounds__(256) void gemm2_kernel(
    const __hip_bfloat16* __restrict__ h, const __hip_bfloat16* __restrict__ w2t,
    const int* __restrict__ counts, const int* __restrict__ bases,
    const int* __restrict__ tiles, const int* __restrict__ ntiles,
    float* __restrict__ o_pair) {
  int y = blockIdx.y;
  if (y >= ntiles[0]) return;
  int packed = tiles[y];
  int e = packed >> 20;
  int m0 = packed & 0xFFFFF;
  int n_e = counts[e];
  int base = bases[e];
  int c0 = blockIdx.x * 128;

  __shared__ short As[4096];
  __shared__ short Bs[4096];

  int t = threadIdx.x;
  int lane = t & 63, wid = t >> 6;

  int rowA = t >> 2;
  int cswz = (t & 3) ^ ((rowA >> 1) & 3);
  int sub = cswz * 8;
  int hr1 = base + m0 + rowA;
  int hr2 = base + m0 + 64 + rowA;
  if (hr1 > 2 * N_TOK - 1) hr1 = 2 * N_TOK - 1;
  if (hr2 > 2 * N_TOK - 1) hr2 = 2 * N_TOK - 1;
  const short* hp = (const short*)h;
  const short* bp = (const short*)w2t + (size_t)e * CDIM * FDIM;
  const short* ag1 = hp + (size_t)hr1 * FDIM + sub;
  const short* ag2 = hp + (size_t)hr2 * FDIM + sub;
  const short* bg1 = bp + (size_t)(c0 + rowA) * FDIM + sub;
  const short* bg2 = bp + (size_t)(c0 + 64 + rowA) * FDIM + sub;

  int aoff = wid * 512;

  f32x4 zero = {0.f, 0.f, 0.f, 0.f};
  f32x4 acc[4][4];
#pragma unroll
  for (int i = 0; i < 4; i++)
#pragma unroll
    for (int j = 0; j < 4; j++) acc[i][j] = zero;

  int wm = (wid & 1) * 64, wn = (wid >> 1) * 64;
  int rsel = lane & 15;
  int kq_swz = (((lane >> 4) ^ ((lane >> 1) & 3))) * 8;

  for (int kk = 0; kk < FDIM; kk += 32) {
    __syncthreads();
    gl2lds16(ag1 + kk, As + aoff);
    gl2lds16(ag2 + kk, As + 2048 + aoff);
    gl2lds16(bg1 + kk, Bs + aoff);
    gl2lds16(bg2 + kk, Bs + 2048 + aoff);
    __syncthreads();
    bf16x8 af[4], bfr[4];
#pragma unroll
    for (int i = 0; i < 4; i++)
      af[i] = *(const bf16x8*)(As + (wm + i * 16 + rsel) * 32 + kq_swz);
#pragma unroll
    for (int j = 0; j < 4; j++)
      bfr[j] = *(const bf16x8*)(Bs + (wn + j * 16 + rsel) * 32 + kq_swz);
#pragma unroll
    for (int i = 0; i < 4; i++)
#pragma unroll
      for (int j = 0; j < 4; j++)
        acc[i][j] = __builtin_amdgcn_mfma_f32_16x16x32_bf16(af[i], bfr[j], acc[i][j], 0, 0, 0);
  }

  int col = lane & 15;
  int rbase = (lane >> 4) * 4;
#pragma unroll
  for (int i = 0; i < 4; i++) {
#pragma unroll
    for (int r = 0; r < 4; r++) {
      int m = m0 + wm + i * 16 + rbase + r;
      if (m < n_e) {
        size_t orow = (size_t)(base + m) * CDIM;
#pragma unroll
        for (int j = 0; j < 4; j++) {
          int c = c0 + wn + j * 16 + col;
          o_pair[orow + c] = acc[i][j][r];
        }
      }
    }
  }
}

// ---------------- combine: out[tok] = p0*o_pair[s0] + p1*o_pair[s1] ----------------
__global__ __launch_bounds__(256) void combine_kernel(
    const float* __restrict__ o_pair, const int* __restrict__ slot_map,
    const float* __restrict__ pair_prob, float* __restrict__ out) {
  int tok = blockIdx.x;
  int s0 = slot_map[tok * 2 + 0], s1 = slot_map[tok * 2 + 1];
  float p0 = pair_prob[tok * 2 + 0], p1 = pair_prob[tok * 2 + 1];
  const float4* r0 = (const float4*)(o_pair + (size_t)s0 * CDIM);
  const float4* r1 = (const float4*)(o_pair + (size_t)s1 * CDIM);
  float4* op = (float4*)(out + (size_t)tok * CDIM);
  int t = threadIdx.x;
#pragma unroll
  for (int j = 0; j < 2; j++) {
    int i = j * 256 + t;
    float4 a = r0[i], b = r1[i];
    float4 c;
    c.x = p0 * a.x + p1 * b.x;
    c.y = p0 * a.y + p1 * b.y;
    c.z = p0 * a.z + p1 * b.z;
    c.w = p0 * a.w + p1 * b.w;
    op[i] = c;
  }
}

extern "C" void kernel_launch(void* const* d_in, const int* in_sizes, int n_in,
                              void* d_out, int out_size, void* d_ws, size_t ws_size,
                              hipStream_t stream) {
  const float* x  = (const float*)d_in[0];
  const float* wr = (const float*)d_in[1];
  const float* w1 = (const float*)d_in[2];
  const float* w3 = (const float*)d_in[3];
  const float* w2 = (const float*)d_in[4];
  float* out = (float*)d_out;

  char* ws = (char*)d_ws;
  __hip_bfloat16* x_bf = (__hip_bfloat16*)(ws);                 // 16 MiB
  __hip_bfloat16* h    = (__hip_bfloat16*)(ws + 16777216);      // 16 MiB
  __hip_bfloat16* w1t  = (__hip_bfloat16*)(ws + 33554432);      // 32 MiB
  __hip_bfloat16* w3t  = (__hip_bfloat16*)(ws + 67108864);      // 32 MiB
  __hip_bfloat16* w2t  = (__hip_bfloat16*)(ws + 100663296);     // 32 MiB
  // o_pair (8192 x 2048 fp32 = 64 MiB) aliases [w1t, w3t] — both dead after gemm1
  float* o_pair = (float*)(ws + 33554432);
  int* counts  = (int*)(ws + 134217728);
  int* bases   = counts + 8;
  int* cursors = counts + 16;
  int* ntiles  = counts + 24;
  int* pair_expert = (int*)(ws + 134217728 + 128);
  float* pair_prob = (float*)(ws + 134217728 + 128 + 32768);
  int* lists       = (int*)(ws + 134217728 + 128 + 65536);
  int* slot_map    = (int*)(ws + 134217728 + 128 + 98304);
  int* tiles       = (int*)(ws + 134217728 + 128 + 131072);

  hipMemsetAsync(counts, 0, 128, stream);

  // w1,w3: [E][C][F] -> [E][F][C] bf16 ; w2: [E][F][C] -> [E][C][F] bf16
  transpose_to_bf16<<<dim3(FDIM / 64, CDIM / 64, EXP), 256, 0, stream>>>(w1, w1t, CDIM, FDIM);
  transpose_to_bf16<<<dim3(FDIM / 64, CDIM / 64, EXP), 256, 0, stream>>>(w3, w3t, CDIM, FDIM);
  transpose_to_bf16<<<dim3(CDIM / 64, FDIM / 64, EXP), 256, 0, stream>>>(w2, w2t, FDIM, CDIM);

  router_kernel<<<N_TOK, 256, 0, stream>>>(x, wr, x_bf, counts, pair_expert, pair_prob);
  scan_kernel<<<1, 64, 0, stream>>>(counts, bases, tiles, ntiles);
  scatter_kernel<<<N_TOK / 256, 256, 0, stream>>>(pair_expert, bases, cursors, lists, slot_map);

  gemm1_kernel<<<dim3(FDIM / 64, MAX_TILES), 256, 0, stream>>>(
      x_bf, w1t, w3t, counts, bases, lists, tiles, ntiles, h);
  gemm2_kernel<<<dim3(CDIM / 128, MAX_TILES), 256, 0, stream>>>(
      h, w2t, counts, bases, tiles, ntiles, o_pair);
  combine_kernel<<<N_TOK, 256, 0, stream>>>(o_pair, slot_map, pair_prob, out);
}